// Round 1
// baseline (81.780 us; speedup 1.0000x reference)
//
#include <hip/hip_runtime.h>
#include <hip/hip_bf16.h>

typedef unsigned short u16;
typedef __attribute__((ext_vector_type(8))) short bf16x8;
typedef __attribute__((ext_vector_type(4))) float f32x4;
typedef __attribute__((ext_vector_type(4))) unsigned short u16x4;

// Round x/scale to nearest e4m3 (saturating to 448), then re-scale.
// Exact bit-math version of the reference's floor(log2())/round pipeline.
__device__ __forceinline__ float mx_e4m3(float x, float inv_scale, float scale) {
    float v  = x * inv_scale;            // exact: power-of-two scale
    float av = fabsf(v);
    int e = (int)(__float_as_uint(av) >> 23) - 127;   // floor(log2(av)) for normals
    e = e < -6 ? -6 : (e > 8 ? 8 : e);                // clip to e4m3 normal range
    float qs = __uint_as_float((unsigned)(130 - e) << 23); // 2^(3-e)
    float qm = __uint_as_float((unsigned)(124 + e) << 23); // 2^(e-3) = quantum
    float q  = fminf(rintf(av * qs) * qm, 448.0f);    // rintf == round-half-even
    return copysignf(q, v) * scale;
}

// shared_exp = floor(log2(amax)) - 8 ; scale = 2^shared_exp (power of two)
__device__ __forceinline__ void block_scale(float amax, float& scale, float& inv_scale) {
    int be = (int)(__float_as_uint(amax) >> 23);   // biased exponent, amax >= 0
    be = be < 8 ? 8 : be;                          // guard: absurdly tiny/zero blocks -> 0 anyway
    scale     = __uint_as_float((unsigned)(be - 8) << 23);   // 2^(be-135)
    inv_scale = __uint_as_float((unsigned)(262 - be) << 23); // 2^(135-be)
}

// Quantize the 256x256 weight to bf16 fake-quant values, stored TRANSPOSED:
// Bq[n*256 + k] = quant(W[k*256 + n]).  MX blocks are 32 consecutive n at fixed k.
__global__ void wq_kernel(const float* __restrict__ W, u16* __restrict__ Bq) {
    const int t  = blockIdx.x * blockDim.x + threadIdx.x; // 16384 threads
    const int f  = t * 4;
    const int k  = f >> 8;
    const int n0 = f & 255;
    const float4 v = *(const float4*)(W + f);
    float am = fmaxf(fmaxf(fabsf(v.x), fabsf(v.y)), fmaxf(fabsf(v.z), fabsf(v.w)));
    am = fmaxf(am, __shfl_xor(am, 1));   // 8 lanes x 4 elems = one 32-elem MX block
    am = fmaxf(am, __shfl_xor(am, 2));
    am = fmaxf(am, __shfl_xor(am, 4));
    float sc, inv; block_scale(am, sc, inv);
    Bq[(size_t)(n0 + 0) * 256 + k] = (u16)(__float_as_uint(mx_e4m3(v.x, inv, sc)) >> 16);
    Bq[(size_t)(n0 + 1) * 256 + k] = (u16)(__float_as_uint(mx_e4m3(v.y, inv, sc)) >> 16);
    Bq[(size_t)(n0 + 2) * 256 + k] = (u16)(__float_as_uint(mx_e4m3(v.z, inv, sc)) >> 16);
    Bq[(size_t)(n0 + 3) * 256 + k] = (u16)(__float_as_uint(mx_e4m3(v.w, inv, sc)) >> 16);
}

// One block: 64 rows x 256 cols output, full K=256.
// 4 waves; wave w owns cols [64w, 64w+64). MFMA 16x16x32 bf16.
__global__ void __launch_bounds__(256, 2)
mx_gemm(const float* __restrict__ X, const u16* __restrict__ Bq,
        const float* __restrict__ bias, float* __restrict__ out)
{
    __shared__ u16 A[64][264];           // +8 pad: ds_read_b128 2-way (free) conflicts
    const int tid = threadIdx.x;
    const int w   = tid >> 6;
    const int l   = tid & 63;
    const size_t row0 = (size_t)blockIdx.x * 64;

    // ---- Phase 1: load + MX-quantize 16 rows per wave into LDS (bf16) ----
    {
        const int kc = l * 4;            // this lane's 4 K-elements
        #pragma unroll
        for (int it = 0; it < 16; ++it) {
            const int r = w * 16 + it;
            const float4 v = *(const float4*)(X + (row0 + r) * 256 + kc);
            float am = fmaxf(fmaxf(fabsf(v.x), fabsf(v.y)), fmaxf(fabsf(v.z), fabsf(v.w)));
            am = fmaxf(am, __shfl_xor(am, 1));  // lanes 8g..8g+7 = one 32-elem MX block
            am = fmaxf(am, __shfl_xor(am, 2));
            am = fmaxf(am, __shfl_xor(am, 4));
            float sc, inv; block_scale(am, sc, inv);
            u16x4 p;
            p.x = (u16)(__float_as_uint(mx_e4m3(v.x, inv, sc)) >> 16);
            p.y = (u16)(__float_as_uint(mx_e4m3(v.y, inv, sc)) >> 16);
            p.z = (u16)(__float_as_uint(mx_e4m3(v.z, inv, sc)) >> 16);
            p.w = (u16)(__float_as_uint(mx_e4m3(v.w, inv, sc)) >> 16);
            *(u16x4*)&A[r][kc] = p;
        }
    }
    __syncthreads();

    // ---- Phase 2: MFMA.  A from LDS, B frags straight from L2-resident Bq ----
    const int lr = l & 15;   // row (A) / col (B,C)
    const int lg = l >> 4;   // k-group
    f32x4 acc[4][4] = {};
    const u16* bb = Bq + (size_t)(w * 64 + lr) * 256 + lg * 8;
    #pragma unroll
    for (int ks = 0; ks < 8; ++ks) {
        bf16x8 af[4], bf[4];
        #pragma unroll
        for (int rt = 0; rt < 4; ++rt)
            af[rt] = *(const bf16x8*)&A[rt * 16 + lr][ks * 32 + lg * 8];
        #pragma unroll
        for (int ct = 0; ct < 4; ++ct)
            bf[ct] = *(const bf16x8*)(bb + (size_t)ct * 16 * 256 + ks * 32);
        #pragma unroll
        for (int rt = 0; rt < 4; ++rt)
            #pragma unroll
            for (int ct = 0; ct < 4; ++ct)
                acc[rt][ct] = __builtin_amdgcn_mfma_f32_16x16x32_bf16(
                    af[rt], bf[ct], acc[rt][ct], 0, 0, 0);
    }

    // ---- Epilogue: bias + store (C/D: col=lane&15, row=(lane>>4)*4+reg) ----
    float bv[4];
    #pragma unroll
    for (int ct = 0; ct < 4; ++ct) bv[ct] = bias[w * 64 + ct * 16 + lr];
    #pragma unroll
    for (int rt = 0; rt < 4; ++rt)
        #pragma unroll
        for (int ct = 0; ct < 4; ++ct)
            #pragma unroll
            for (int rg = 0; rg < 4; ++rg) {
                const size_t row = row0 + rt * 16 + lg * 4 + rg;
                out[row * 256 + w * 64 + ct * 16 + lr] = acc[rt][ct][rg] + bv[ct];
            }
}

extern "C" void kernel_launch(void* const* d_in, const int* in_sizes, int n_in,
                              void* d_out, int out_size, void* d_ws, size_t ws_size,
                              hipStream_t stream) {
    const float* x    = (const float*)d_in[0];
    const float* wk   = (const float*)d_in[1];
    const float* bias = (const float*)d_in[2];
    float* out = (float*)d_out;
    u16* Bq    = (u16*)d_ws;              // 256*256 bf16 = 128 KB scratch
    const int M = in_sizes[0] / 256;      // 131072 rows
    wq_kernel<<<64, 256, 0, stream>>>(wk, Bq);
    mx_gemm<<<M / 64, 256, 0, stream>>>(x, Bq, bias, out);
}

// Round 2
// 70.014 us; speedup vs baseline: 1.1681x; 1.1681x over previous
//
#include <hip/hip_runtime.h>
#include <hip/hip_bf16.h>

typedef unsigned short u16;
typedef unsigned int u32;
typedef __attribute__((ext_vector_type(8))) short bf16x8;
typedef __attribute__((ext_vector_type(4))) float f32x4;
typedef __attribute__((ext_vector_type(2))) float f32x2;
typedef __attribute__((ext_vector_type(4))) unsigned short u16x4;

// shared_exp = floor(log2(amax)) - 8 ; scale = 2^shared_exp (power of two)
__device__ __forceinline__ void block_scale(float amax, float& scale, float& inv_scale) {
    int be = (int)(__float_as_uint(amax) >> 23);   // biased exponent, amax >= 0
    be = be < 8 ? 8 : be;                          // tiny/zero blocks quantize to 0 anyway
    scale     = __uint_as_float((unsigned)(be - 8) << 23);   // 2^(be-135)
    inv_scale = __uint_as_float((unsigned)(262 - be) << 23); // 2^(135-be)
}

#if __has_builtin(__builtin_amdgcn_cvt_pk_fp8_f32) && __has_builtin(__builtin_amdgcn_cvt_pk_f32_fp8)
#define HAS_HW_FP8 1
#else
#define HAS_HW_FP8 0
#endif

#if !HAS_HW_FP8
// Fallback: exact bit-math e4m3 RNE (verified in round 0)
__device__ __forceinline__ float mx_e4m3(float x, float inv_scale, float scale) {
    float v  = x * inv_scale;
    float av = fabsf(v);
    int e = (int)(__float_as_uint(av) >> 23) - 127;
    e = e < -6 ? -6 : (e > 8 ? 8 : e);
    float qs = __uint_as_float((unsigned)(130 - e) << 23);
    float qm = __uint_as_float((unsigned)(124 + e) << 23);
    float q  = fminf(rintf(av * qs) * qm, 448.0f);
    return copysignf(q, v) * scale;
}
#endif

// Quantize 4 elems to e4m3 grid (RNE, saturate 448), return bf16 bits of value*scale.
// bf16 conversion is exact (e4m3 has 4 significand bits, bf16 has 8).
__device__ __forceinline__ u16x4 quant4(float4 v, float inv, float sc) {
    u16x4 r;
#if HAS_HW_FP8
    // pre-clamp to +-448 so HW overflow semantics never matter (matches ref's min(q,448))
    float a = fminf(fmaxf(v.x * inv, -448.f), 448.f);
    float b = fminf(fmaxf(v.y * inv, -448.f), 448.f);
    float c = fminf(fmaxf(v.z * inv, -448.f), 448.f);
    float d = fminf(fmaxf(v.w * inv, -448.f), 448.f);
    int p = __builtin_amdgcn_cvt_pk_fp8_f32(a, b, 0, false);   // RNE f32->e4m3 (OCP on gfx950)
    p     = __builtin_amdgcn_cvt_pk_fp8_f32(c, d, p, true);
    f32x2 lo = __builtin_amdgcn_cvt_pk_f32_fp8(p, false);      // exact e4m3->f32
    f32x2 hi = __builtin_amdgcn_cvt_pk_f32_fp8(p, true);
    r.x = (u16)(__float_as_uint(lo[0] * sc) >> 16);
    r.y = (u16)(__float_as_uint(lo[1] * sc) >> 16);
    r.z = (u16)(__float_as_uint(hi[0] * sc) >> 16);
    r.w = (u16)(__float_as_uint(hi[1] * sc) >> 16);
#else
    r.x = (u16)(__float_as_uint(mx_e4m3(v.x, inv, sc)) >> 16);
    r.y = (u16)(__float_as_uint(mx_e4m3(v.y, inv, sc)) >> 16);
    r.z = (u16)(__float_as_uint(mx_e4m3(v.z, inv, sc)) >> 16);
    r.w = (u16)(__float_as_uint(mx_e4m3(v.w, inv, sc)) >> 16);
#endif
    return r;
}

// Quantize 256x256 weight to bf16 fake-quant, stored TRANSPOSED: Bq[n*256+k].
// MX blocks are 32 consecutive n at fixed k (flat reshape of row-major (K,N)).
__global__ void wq_kernel(const float* __restrict__ W, u16* __restrict__ Bq) {
    const int t  = blockIdx.x * blockDim.x + threadIdx.x;
    const int f  = t * 4;
    const int k  = f >> 8;
    const int n0 = f & 255;
    const float4 v = *(const float4*)(W + f);
    float am = fmaxf(fmaxf(fabsf(v.x), fabsf(v.y)), fmaxf(fabsf(v.z), fabsf(v.w)));
    am = fmaxf(am, __shfl_xor(am, 1));   // 8 lanes x 4 elems = one 32-elem MX block
    am = fmaxf(am, __shfl_xor(am, 2));
    am = fmaxf(am, __shfl_xor(am, 4));
    float sc, inv; block_scale(am, sc, inv);
    u16x4 q = quant4(v, inv, sc);
    Bq[(size_t)(n0 + 0) * 256 + k] = q.x;
    Bq[(size_t)(n0 + 1) * 256 + k] = q.y;
    Bq[(size_t)(n0 + 2) * 256 + k] = q.z;
    Bq[(size_t)(n0 + 3) * 256 + k] = q.w;
}

// One block: 64 rows x 256 cols, K=256. 4 waves; wave w owns cols [64w,64w+64).
__global__ void __launch_bounds__(256, 4)
mx_gemm(const float* __restrict__ X, const u16* __restrict__ Bq,
        const float* __restrict__ bias, float* __restrict__ out)
{
    __shared__ u16 A[64 * 256];          // 32 KB, XOR-swizzled (byte ^= (row&7)<<4)
    const int tid = threadIdx.x;
    const int w   = tid >> 6;
    const int l   = tid & 63;
    const size_t row0 = (size_t)blockIdx.x * 64;

    // ---- Phase 1: issue ALL 16 row-loads first (deep vmcnt pipeline), then quantize ----
    {
        const int kc = l * 4;
        float4 xv[16];
        #pragma unroll
        for (int it = 0; it < 16; ++it)
            xv[it] = *(const float4*)(X + (row0 + w * 16 + it) * 256 + kc);
        #pragma unroll
        for (int it = 0; it < 16; ++it) {
            const int r = w * 16 + it;
            float4 v = xv[it];
            float am = fmaxf(fmaxf(fabsf(v.x), fabsf(v.y)), fmaxf(fabsf(v.z), fabsf(v.w)));
            am = fmaxf(am, __shfl_xor(am, 1));  // 8-lane group = one 32-elem MX block (along K)
            am = fmaxf(am, __shfl_xor(am, 2));
            am = fmaxf(am, __shfl_xor(am, 4));
            float sc, inv; block_scale(am, sc, inv);
            u16x4 q = quant4(v, inv, sc);
            // swizzled write: all lanes same row -> uniform XOR, conflict-free
            char* dst = (char*)A + (((u32)(r * 512 + l * 8)) ^ ((u32)(r & 7) << 4));
            *(u16x4*)dst = q;
        }
    }
    __syncthreads();

    // ---- Phase 2: MFMA with 1-deep B prefetch. SWAPPED operands: mfma(B,A) so each
    //      lane's 4 acc regs are 4 consecutive n -> float4 stores. ----
    const int lr = l & 15;
    const int lg = l >> 4;
    f32x4 acc[4][4] = {};
    const u16* bb = Bq + (size_t)(w * 64 + lr) * 256 + lg * 8;

    bf16x8 bcur[4], bnxt[4];
    #pragma unroll
    for (int ct = 0; ct < 4; ++ct)
        bcur[ct] = *(const bf16x8*)(bb + (size_t)ct * 16 * 256);

    #pragma unroll
    for (int ks = 0; ks < 8; ++ks) {
        bf16x8 af[4];
        #pragma unroll
        for (int rt = 0; rt < 4; ++rt) {
            const int row = rt * 16 + lr;
            const u32 off = ((u32)(row * 512 + ks * 64 + lg * 16)) ^ ((u32)(lr & 7) << 4);
            af[rt] = *(const bf16x8*)((const char*)A + off);
        }
        if (ks < 7) {
            #pragma unroll
            for (int ct = 0; ct < 4; ++ct)
                bnxt[ct] = *(const bf16x8*)(bb + (size_t)ct * 16 * 256 + (ks + 1) * 32);
        }
        #pragma unroll
        for (int rt = 0; rt < 4; ++rt)
            #pragma unroll
            for (int ct = 0; ct < 4; ++ct)
                acc[rt][ct] = __builtin_amdgcn_mfma_f32_16x16x32_bf16(
                    bcur[ct], af[rt], acc[rt][ct], 0, 0, 0);
        if (ks < 7) {
            #pragma unroll
            for (int ct = 0; ct < 4; ++ct) bcur[ct] = bnxt[ct];
        }
    }

    // ---- Epilogue: lane holds C[m = rt*16+lr][n = w*64+ct*16+lg*4 .. +3] ----
    #pragma unroll
    for (int ct = 0; ct < 4; ++ct) {
        const float4 bv = *(const float4*)(bias + w * 64 + ct * 16 + lg * 4);
        #pragma unroll
        for (int rt = 0; rt < 4; ++rt) {
            f32x4 o = acc[rt][ct];
            o[0] += bv.x; o[1] += bv.y; o[2] += bv.z; o[3] += bv.w;
            *(f32x4*)(out + (row0 + rt * 16 + lr) * 256 + w * 64 + ct * 16 + lg * 4) = o;
        }
    }
}

extern "C" void kernel_launch(void* const* d_in, const int* in_sizes, int n_in,
                              void* d_out, int out_size, void* d_ws, size_t ws_size,
                              hipStream_t stream) {
    const float* x    = (const float*)d_in[0];
    const float* wk   = (const float*)d_in[1];
    const float* bias = (const float*)d_in[2];
    float* out = (float*)d_out;
    u16* Bq    = (u16*)d_ws;              // 256*256 bf16 = 128 KB scratch
    const int M = in_sizes[0] / 256;      // 131072 rows
    wq_kernel<<<64, 256, 0, stream>>>(wk, Bq);
    mx_gemm<<<M / 64, 256, 0, stream>>>(x, Bq, bias, out);
}